// Round 1
// 170.059 us; speedup vs baseline: 1.0116x; 1.0116x over previous
//
#include <hip/hip_runtime.h>

using frag_t = __attribute__((ext_vector_type(8))) short;   // 8 x bf16 (4 VGPRs)
using f32x4  = __attribute__((ext_vector_type(4))) float;   // MFMA C/D

#define L2E 1.4426950408889634f

#if __has_builtin(__builtin_amdgcn_exp2f)
#define EXP2(x) __builtin_amdgcn_exp2f(x)   // raw v_exp_f32 (no denormal fixup seq)
#else
#define EXP2(x) exp2f(x)
#endif

constexpr int B_  = 2, S_ = 2048, D_ = 1024, H_ = 16, HD_ = 64;
constexpr int M_  = B_ * S_;      // 4096
constexpr float QSCALE = 0.125f * L2E;   // fold softmax log2e into Q

__device__ __forceinline__ ushort f2bf(float f) {
  union { float f; unsigned u; } v; v.f = f;
  unsigned u = v.u;
  unsigned r = (u + 0x7FFFu + ((u >> 16) & 1u)) >> 16;  // round-nearest-even
  return (ushort)r;
}
__device__ __forceinline__ unsigned pk_bf2(float a, float b) {  // round-half-up pack
  unsigned ua = __float_as_uint(a) + 0x8000u;
  unsigned ub = __float_as_uint(b) + 0x8000u;
  return (ua >> 16) | (ub & 0xFFFF0000u);
}

// async 16B/lane global->LDS (lds dest = wave-uniform base + lane*16) [m97]
__device__ __forceinline__ void gld_lds16(const ushort* g, ushort* l) {
  __builtin_amdgcn_global_load_lds((const __attribute__((address_space(1))) void*)g,
                                   (__attribute__((address_space(3))) void*)l, 16, 0, 0);
}

// ---------- fused prep: x->bf16  |  Wqkv^T->bf16  |  Wproj^T->bf16 ----------
__global__ __launch_bounds__(256) void k_prep(
    const float* __restrict__ x, const float* __restrict__ Wqkv,
    const float* __restrict__ Wproj,
    ushort* __restrict__ Xbf, ushort* __restrict__ Wqt, ushort* __restrict__ Wpt) {
  int blk = blockIdx.x, tid = threadIdx.x;
  if (blk < 1024) {                                 // x convert: 4096 elems/block
    size_t base = (size_t)blk * 4096 + tid * 4;
    #pragma unroll
    for (int i = 0; i < 4; ++i) {
      float4 f = *(const float4*)(x + base + i * 1024);
      ushort4 o;
      o.x = f2bf(f.x); o.y = f2bf(f.y); o.z = f2bf(f.z); o.w = f2bf(f.w);
      *(ushort4*)(Xbf + base + i * 1024) = o;
    }
  } else {                                          // W [K,N] -> W^T [N,K] bf16, 64x64 tile
    __shared__ float tile[64][65];
    const float* in; ushort* out; int N, K, bx, by;
    if (blk < 1024 + 768) { int b2 = blk - 1024; in = Wqkv;  out = Wqt; N = 3072; K = 1024; bx = b2 % 48; by = b2 / 48; }
    else                  { int b2 = blk - 1792; in = Wproj; out = Wpt; N = 1024; K = 1024; bx = b2 % 16; by = b2 / 16; }
    int n0 = bx * 64, k0 = by * 64;
    int tx = tid & 63, ty = tid >> 6;               // (64,4)
    #pragma unroll
    for (int i = 0; i < 16; ++i)
      tile[ty + i * 4][tx] = in[(size_t)(k0 + ty + i * 4) * N + n0 + tx];
    __syncthreads();
    #pragma unroll
    for (int i = 0; i < 16; ++i)
      out[(size_t)(n0 + ty + i * 4) * K + k0 + tx] = f2bf(tile[tx][ty + i * 4]);
  }
}

// ---------- 256x256 8-phase QKV GEMM (m201 template ported to plain HIP) ----------
// BM=BN=256, BK=64, 8 waves (2M x 4N), per-wave 128x64 output (8x4 16x16 frags).
// LDS 128 KiB: [buf2][A|B][khalf2][256 rows][32 k] bf16. Half-tile = K-half
// (256x32 = 16 KB), staged one per phase (2x gld_lds16/thread). Chunk-XOR
// swizzle c_stored = c ^ ((row>>2)&3): read frag pos = quad ^ ((li>>2)&3),
// 2-way max per 16-lane phase (same conflict profile as validated R10 swz).
// T4: counted s_waitcnt vmcnt(4) at phases 4/8 only (retires exactly the next
// K-tile's 4 halves; 2 half-tiles stay in flight). T5: setprio around MFMA.
// T1: bijective XCD swizzle (192 WGs, 192%8==0). Tail iterations stage
// clamped (dead) tiles to keep vmcnt bookkeeping uniform; drained before
// the epilogue reuses LDS for the V^T transpose.
__global__ __launch_bounds__(512, 2) void k_gemm8(
    const ushort* __restrict__ A, const ushort* __restrict__ Bt,
    const float* __restrict__ bias,
    ushort* __restrict__ Qo, ushort* __restrict__ Ko, ushort* __restrict__ Vo) {
  __shared__ ushort smem[65536];                    // 128 KiB
  int tid = threadIdx.x;
  int lane = tid & 63, wave = tid >> 6;
  int quad = lane >> 4, li = lane & 15;
  int wm = wave >> 2, wn = wave & 3;
  int wg = blockIdx.x;                              // 192 = 16(M) x 12(N)
  int swz = (wg & 7) * 24 + (wg >> 3);              // contiguous 24-chunk per XCD
  int by = swz / 12, bx = swz % 12;
  int m0 = by * 256, n0 = bx * 256;
  const ushort* Asrc = A  + (size_t)m0 * 1024;
  const ushort* Bsrc = Bt + (size_t)n0 * 1024;
  int srow   = lane >> 2;                           // 16 rows / gld_lds
  int schunk = (lane & 3) ^ ((lane >> 4) & 3);      // stored pos -> source chunk
  int pos    = (quad ^ ((li >> 2) & 3)) * 8;        // frag read position (elems)

#define STG(BI, ISB, KS, KT) do { \
    const ushort* _s = (ISB) ? Bsrc : Asrc; \
    ushort* _d = &smem[((BI)*4 + (ISB)*2 + (KS)) * 8192]; \
    _Pragma("unroll") \
    for (int j = 0; j < 2; ++j) \
      gld_lds16(&_s[(size_t)(j*128 + wave*16 + srow) * 1024 + (KT)*64 + (KS)*32 + schunk*8], \
                &_d[(j*128 + wave*16) * 32]); \
  } while (0)

  f32x4 acc[8][4] = {};
  frag_t af[8], bf[2];

#define PH(BI, KS, NH, STGS, W4) do { \
    if ((NH) == 0) { \
      _Pragma("unroll") \
      for (int mi = 0; mi < 8; ++mi) \
        af[mi] = *(const frag_t*)&smem[((BI)*4 + (KS)) * 8192 + (wm*128 + mi*16 + li) * 32 + pos]; \
    } \
    _Pragma("unroll") \
    for (int nj = 0; nj < 2; ++nj) \
      bf[nj] = *(const frag_t*)&smem[((BI)*4 + 2 + (KS)) * 8192 + (wn*64 + ((NH)*2 + nj)*16 + li) * 32 + pos]; \
    STGS; \
    if (W4) asm volatile("s_waitcnt vmcnt(4)" ::: "memory"); \
    asm volatile("s_barrier" ::: "memory"); \
    __builtin_amdgcn_s_setprio(1); \
    _Pragma("unroll") \
    for (int mi = 0; mi < 8; ++mi) { \
      acc[mi][(NH)*2+0] = __builtin_amdgcn_mfma_f32_16x16x32_bf16(af[mi], bf[0], acc[mi][(NH)*2+0], 0, 0, 0); \
      acc[mi][(NH)*2+1] = __builtin_amdgcn_mfma_f32_16x16x32_bf16(af[mi], bf[1], acc[mi][(NH)*2+1], 0, 0, 0); \
    } \
    __builtin_amdgcn_s_setprio(0); \
    asm volatile("s_barrier" ::: "memory"); \
  } while (0)

  // prologue: tile0 complete + tile1's K0 halves issued; vmcnt(4) retires
  // exactly tile0 (8 loads), leaves 2 half-tiles (4 loads) in flight.
  STG(0,0,0,0); STG(0,1,0,0); STG(0,0,1,0); STG(0,1,1,0);
  STG(1,0,0,1); STG(1,1,0,1);
  asm volatile("s_waitcnt vmcnt(4)" ::: "memory");
  asm volatile("s_barrier" ::: "memory");

  for (int it = 0; it < 8; ++it) {                  // 2 K-tiles / iter, NT=16
    int t1 = 2*it + 1;
    int t2 = (2*it + 2 < 16) ? 2*it + 2 : 15;       // clamp: dead stage keeps
    int t3 = (2*it + 3 < 16) ? 2*it + 3 : 15;       //   vmcnt counts uniform
    PH(0,0,0, STG(1,0,1,t1), 0);                    // P1: +A[t+1].K1
    PH(0,0,1, STG(1,1,1,t1), 0);                    // P2: +B[t+1].K1
    PH(0,1,0, STG(0,0,0,t2), 0);                    // P3: +A[t+2].K0
    PH(0,1,1, STG(0,1,0,t2), 1);                    // P4: +B[t+2].K0, vmcnt(4)
    PH(1,0,0, STG(0,0,1,t2), 0);                    // P5: +A[t+2].K1
    PH(1,0,1, STG(0,1,1,t2), 0);                    // P6: +B[t+2].K1
    PH(1,1,0, STG(1,0,0,t3), 0);                    // P7: +A[t+3].K0
    PH(1,1,1, STG(1,1,0,t3), 1);                    // P8: +B[t+3].K0, vmcnt(4)
  }
#undef PH
#undef STG

  asm volatile("s_waitcnt vmcnt(0)" ::: "memory");  // drain dead stages before LDS reuse
  __syncthreads();

  // epilogue: C row = quad*4+r, col = li  [m89/m91]; wave tile 128(M)x64(N)
  int which = (n0 + wn * 64) >> 10;                 // wave-uniform: Q/K/V region
  if (which < 2) {                                  // Q / K: [bh][s][hd]
    #pragma unroll
    for (int ni = 0; ni < 4; ++ni) {
      int gcol = n0 + wn * 64 + ni * 16 + li;
      float bv = bias[gcol];
      int d = gcol & 1023, h = d >> 6, hd = d & 63;
      #pragma unroll
      for (int mi = 0; mi < 8; ++mi)
        #pragma unroll
        for (int r = 0; r < 4; ++r) {
          int grow = m0 + wm * 128 + mi * 16 + quad * 4 + r;
          int b = grow >> 11, s = grow & 2047;
          size_t off = (((size_t)b * H_ + h) * S_ + s) * HD_ + hd;
          float v = acc[mi][ni][r] + bv;
          if (which == 0) Qo[off] = f2bf(v * QSCALE);
          else            Ko[off] = f2bf(v);
        }
    }
  } else {                                          // V -> sigma-permuted V^T
    // wave-private 64(hd) x 128(s) transpose buffer in now-dead main LDS;
    // chunk-XOR swizzle (col ^ ((row&7)<<3)) instead of pad (no room for pad).
    ushort* vl = &smem[wave * 8192];
    #pragma unroll
    for (int ni = 0; ni < 4; ++ni) {
      int row = ni * 16 + li;                       // hd 0..63
      float bv = bias[n0 + wn * 64 + row];
      int rx = (row & 7) << 3;
      #pragma unroll
      for (int mi = 0; mi < 8; ++mi)
        #pragma unroll
        for (int r = 0; r < 4; ++r) {               // sigma(16q+4r+mi') = 16mi'+4q+r
          int col = (mi >> 2) * 64 + quad * 16 + r * 4 + (mi & 3);
          vl[row * 128 + (col ^ rx)] = f2bf(acc[mi][ni][r] + bv);
        }
    }                                               // wave-private: in-order ds
    int h  = ((n0 & 1023) + wn * 64) >> 6;          // head (wave n-range = 1 head)
    int b  = m0 >> 11;
    int s0 = (m0 & 2047) + wm * 128;                // wave's 128-key span (64-aligned)
    size_t vbase = ((size_t)b * H_ + h) * HD_ * S_;
    #pragma unroll
    for (int i = 0; i < 16; ++i) {
      int row = i * 4 + quad;                       // hd
      int col = li * 8;                             // permuted s chunk (16B)
      *(uint4*)&Vo[vbase + (size_t)row * S_ + s0 + col] =
          *(const uint4*)&vl[row * 128 + (col ^ ((row & 7) << 3))];
    }
  }
}

// ---------- bf16 MFMA GEMM (m97 structure) — kept for the proj epilogue ----------
template <int EPI>
__global__ __launch_bounds__(256) void k_gemm(
    const ushort* __restrict__ A, const ushort* __restrict__ Bt,
    const float* __restrict__ bias,
    ushort* __restrict__ Qo, ushort* __restrict__ Ko, ushort* __restrict__ Vo,
    float* __restrict__ Co, int N, int K) {
  constexpr int BM = (EPI == 0) ? 128 : 64;
  constexpr int BN = 64, BK = 64;
  constexpr int MI = (EPI == 0) ? 4 : 2, NI = 2;
  __shared__ ushort smem[(BM + BN) * BK];
  ushort* As = smem;
  ushort* Bs = smem + BM * BK;
  int tid  = threadIdx.x;
  int lane = tid & 63, wave = tid >> 6;
  int quad = lane >> 4, li = lane & 15;
  int mbase = (wave >> 1) * (MI * 16);              // 2x2 waves
  int nbase = (wave & 1) * 32;
  int m0 = blockIdx.y * BM, n0 = blockIdx.x * BN;
  int srow = lane >> 3;                             // within a wave: 8 rows x 128B
  int scol = ((lane & 7) ^ srow) * 8;               // XOR-swizzled global chunk
  f32x4 acc[MI][NI] = {};
  for (int k0 = 0; k0 < K; k0 += BK) {
    if (EPI == 0) {
      #pragma unroll
      for (int i = 0; i < 4; ++i) {                 // A: 128 rows
        int rbase = i * 32 + wave * 8;
        gld_lds16(&A[(size_t)(m0 + rbase + srow) * K + k0 + scol], &As[rbase * BK]);
      }
    } else {
      #pragma unroll
      for (int i = 0; i < 2; ++i) {                 // A: 64 rows
        int rbase = wave * 16 + i * 8;
        gld_lds16(&A[(size_t)(m0 + rbase + srow) * K + k0 + scol], &As[rbase * BK]);
      }
    }
    #pragma unroll
    for (int i = 0; i < 2; ++i) {                   // B: 64 rows
      int rbase = wave * 16 + i * 8;
      gld_lds16(&Bt[(size_t)(n0 + rbase + srow) * K + k0 + scol], &Bs[rbase * BK]);
    }
    __syncthreads();                                // drains vmcnt (compiler-emitted)
    #pragma unroll
    for (int ks = 0; ks < 2; ++ks) {
      frag_t af[MI], bf[NI];
      #pragma unroll
      for (int mi = 0; mi < MI; ++mi)
        af[mi] = *(const frag_t*)&As[(mbase + mi * 16 + li) * BK + (((ks * 4 + quad) ^ (li & 7)) * 8)];
      #pragma unroll
      for (int ni = 0; ni < NI; ++ni)
        bf[ni] = *(const frag_t*)&Bs[(nbase + ni * 16 + li) * BK + (((ks * 4 + quad) ^ (li & 7)) * 8)];
      #pragma unroll
      for (int mi = 0; mi < MI; ++mi)
        #pragma unroll
        for (int ni = 0; ni < NI; ++ni)
          acc[mi][ni] = __builtin_amdgcn_mfma_f32_16x16x32_bf16(af[mi], bf[ni], acc[mi][ni], 0, 0, 0);
    }
    __syncthreads();
  }
  // epilogue: C/D layout row = quad*4+reg, col = li  [measured m89/m91]
  if (EPI == 1) {
    #pragma unroll
    for (int mi = 0; mi < MI; ++mi)
      #pragma unroll
      for (int ni = 0; ni < NI; ++ni) {
        int gcol = n0 + nbase + ni * 16 + li;
        float bv = bias[gcol];
        #pragma unroll
        for (int r = 0; r < 4; ++r) {
          int grow = m0 + mbase + mi * 16 + quad * 4 + r;
          Co[(size_t)grow * N + gcol] = acc[mi][ni][r] + bv;
        }
      }
  }
}

// ---------- causal flash attention (validated R10 version) ----------
// WG = 4 waves = one 64-row q-tile; double-buffered LDS K/V via async
// global_load_lds; LDS = 40960 B -> 4 WGs/CU. sigma-permuted key basis
// (shared with V^T): lane's 4 p-values pack to one ds_write_b64/row.
// l via MFMA ones-B (row-sum broadcast). Raw v_exp_f32; log2e in Q.
__global__ __launch_bounds__(256) void k_attn(
    const ushort* __restrict__ Q, const ushort* __restrict__ K,
    const ushort* __restrict__ Vt, ushort* __restrict__ O) {
  __shared__ ushort Kbuf[2][64 * 64];
  __shared__ ushort Vbuf[2][64 * 64];
  __shared__ ushort Plds[4 * 16 * 64];             // per-wave P buffer (C->A transform)
  int lane = threadIdx.x & 63, wave = threadIdx.x >> 6;
  int quad = lane >> 4, li = lane & 15;
  int bh = blockIdx.x;                             // x = bh: XCD round-robin, K/V hot in L2
  int qb = 31 - (int)blockIdx.y;                   // heavy q-tiles dispatch first
  int b = bh >> 4, h = bh & 15;
  int q0 = qb * 64 + wave * 16;
  const ushort* Qb = Q  + (size_t)bh * S_ * HD_;
  const ushort* Kb = K  + (size_t)bh * S_ * HD_;
  const ushort* Vb = Vt + (size_t)bh * HD_ * S_;
  ushort* Pw = &Plds[wave * 1024];

  frag_t qf[2];  // A-operand: m = li, k = quad*8+j  [measured m120]
  #pragma unroll
  for (int ks = 0; ks < 2; ++ks)
    qf[ks] = *(const frag_t*)&Qb[(size_t)(q0 + li) * HD_ + ks * 32 + quad * 8];

  frag_t ones;                                     // bf16 1.0 splat (B for row-sum MFMA)
  #pragma unroll
  for (int i = 0; i < 8; ++i) ones[i] = (short)0x3F80;

  f32x4 o[4] = {};
  f32x4 lacc = {};                                 // row-sums of P (C-layout, col-broadcast)

  auto stage = [&](int kb, int bi) {
    #pragma unroll
    for (int i = 0; i < 2; ++i) {
      int rt  = wave * 16 + i * 8 + (lane >> 3);   // tile row
      int c16 = (lane & 7) ^ (lane >> 3);          // swizzle: (rt&7) == lane>>3
      gld_lds16(&Kb[(size_t)(kb * 64 + rt) * HD_ + c16 * 8], &Kbuf[bi][(wave * 16 + i * 8) * 64]);
      gld_lds16(&Vb[(size_t)rt * S_ + kb * 64 + c16 * 8],    &Vbuf[bi][(wave * 16 + i * 8) * 64]);
    }
  };

  auto comp = [&](int kb, bool diag, int bi) {
    f32x4 sc[4];
    #pragma unroll
    for (int t = 0; t < 4; ++t) {
      f32x4 a = {};
      #pragma unroll
      for (int ks = 0; ks < 2; ++ks) {
        frag_t kf = *(const frag_t*)&Kbuf[bi][(t * 16 + li) * 64 + (((quad + ks * 4) ^ (li & 7)) * 8)];
        a = __builtin_amdgcn_mfma_f32_16x16x32_bf16(qf[ks], kf, a, 0, 0, 0);
      }
      sc[t] = a;
    }
    if (diag) {
      #pragma unroll
      for (int t = 0; t < 4; ++t) {
        int key = kb * 64 + t * 16 + li;
        #pragma unroll
        for (int r = 0; r < 4; ++r)
          if (key > q0 + quad * 4 + r) sc[t][r] = -1e30f;
      }
    }
    #pragma unroll
    for (int t = 0; t < 4; ++t)
      #pragma unroll
      for (int r = 0; r < 4; ++r)
        sc[t][r] = EXP2(sc[t][r]);                 // masked -> exp2(-1e30) = 0
    #pragma unroll
    for (int r = 0; r < 4; ++r) {                  // pack 4 bf16 (permuted cols 4li..4li+3) -> b64
      int row = quad * 4 + r;
      uint2 w;
      w.x = pk_bf2(sc[0][r], sc[1][r]);
      w.y = pk_bf2(sc[2][r], sc[3][r]);
      *(uint2*)&Pw[row * 64 + ((li ^ (row & 6)) * 4)] = w;
    }
    frag_t pf[2];                                  // wave-private LDS: in-order, no barrier
    #pragma unroll
    for (int ks = 0; ks < 2; ++ks) {
      int g0 = (ks * 4 + quad) * 2;
      pf[ks] = *(const frag_t*)&Pw[li * 64 + ((g0 ^ (li & 6)) * 4)];
    }
    lacc = __builtin_amdgcn_mfma_f32_16x16x32_bf16(pf[0], ones, lacc, 0, 0, 0);
    lacc = __builtin_amdgcn_mfma_f32_16x16x32_bf16(pf[1], ones, lacc, 0, 0, 0);
    #pragma unroll
    for (int t = 0; t < 4; ++t)
      #pragma unroll
      for (int ks = 0; ks < 2; ++ks) {
        frag_t vf = *(const frag_t*)&Vbuf[bi][(t * 16 + li) * 64 + (((quad + ks * 4) ^ (li & 7)) * 8)];
        o[t] = __builtin_amdgcn_mfma_f32_16x16x32_bf16(pf[ks], vf, o[t], 0, 0, 0);
      }
  };

  stage(0, 0);
  __syncthreads();                                 // DMA for kb=0 landed
  for (int kb = 0; kb <= qb; ++kb) {
    if (kb < qb) stage(kb + 1, (kb + 1) & 1);      // async DMA overlaps comp below
    comp(kb, kb == qb, kb & 1);
    __syncthreads();                               // drains DMA + guards buffer reuse
  }

  #pragma unroll
  for (int r = 0; r < 4; ++r) {
    float inv = 1.f / lacc[r];                     // row-sum already broadcast across lanes
    int srow = q0 + quad * 4 + r;
    #pragma unroll
    for (int ht = 0; ht < 4; ++ht)
      O[((size_t)b * S_ + srow) * D_ + h * 64 + ht * 16 + li] = f2bf(o[ht][r] * inv);
  }
}

extern "C" void kernel_launch(void* const* d_in, const int* in_sizes, int n_in,
                              void* d_out, int out_size, void* d_ws, size_t ws_size,
                              hipStream_t stream) {
  (void)in_sizes; (void)n_in; (void)out_size; (void)ws_size;
  const float* x     = (const float*)d_in[0];
  const float* Wqkv  = (const float*)d_in[1];
  const float* bqkv  = (const float*)d_in[2];
  const float* Wproj = (const float*)d_in[3];
  const float* bproj = (const float*)d_in[4];
  float* out = (float*)d_out;

  char* ws = (char*)d_ws;                          // 40 MB used
  ushort* Xbf = (ushort*)(ws);                     //  8 MB  [4096,1024] bf16 (reused as O after attn)
  ushort* Wqt = (ushort*)(ws + (8u  << 20));       //  6 MB  [3072,1024] bf16
  ushort* Wpt = (ushort*)(ws + (14u << 20));       //  2 MB  [1024,1024] bf16
  ushort* Qbf = (ushort*)(ws + (16u << 20));       //  8 MB  [32,2048,64]  (pre-scaled by 0.125*log2e)
  ushort* Kbf = (ushort*)(ws + (24u << 20));       //  8 MB  [32,2048,64]
  ushort* Vtb = (ushort*)(ws + (32u << 20));       //  8 MB  [32,64,2048]  (V^T, sigma-permuted keys)
  ushort* Obf = Xbf;                               // X dead after QKV GEMM

  k_prep<<<dim3(2048), dim3(256), 0, stream>>>(x, Wqkv, Wproj, Xbf, Wqt, Wpt);
  k_gemm8<<<dim3(192), dim3(512), 0, stream>>>(Xbf, Wqt, bqkv, Qbf, Kbf, Vtb);
  k_attn<<<dim3(B_ * H_, 32), dim3(256), 0, stream>>>(Qbf, Kbf, Vtb, Obf);
  k_gemm<1><<<dim3(16, 64), dim3(256), 0, stream>>>(Obf, Wpt, bproj,
                                                    (ushort*)nullptr, (ushort*)nullptr, (ushort*)nullptr,
                                                    out, D_, D_);
}